// Round 8
// baseline (15.990 us; speedup 1.0000x reference)
//
#include <hip/hip_runtime.h>
#include <hip/hip_bf16.h>

#define LOOKBACK 8
#define HID 32
#define TPW 56          // outputs per 64-lane wave (rows j..j+7 stay in-wave)
#define RST 20          // uints per K row (16 used + 4 pad) = 80B stride
#define EPS 1e-6f

// sP (LDS) param layout (floats)
#define WS_AQ  0     // [4][32]
#define WS_CQ  128   // [32]
#define WS_AK  160   // [4][32]
#define WS_CK  288   // [32]
#define WS_AVW 320   // [4]
#define WS_CVW 324   // scalar
#define WS_N   336

__device__ __forceinline__ float phi1(float z) {
    return (z >= 0.0f ? z : 0.01f * z) + 1.0f;
}
__device__ __forceinline__ unsigned pack_bf16(float a, float b) {
    __hip_bfloat162 h = __float22bfloat162_rn(make_float2(a, b));
    return *reinterpret_cast<unsigned*>(&h);
}
__device__ __forceinline__ float blo(unsigned u) {   // packed-first elem (ch 2m)
    return __uint_as_float(u << 16);
}
__device__ __forceinline__ float bhi(unsigned u) {   // ch 2m+1
    return __uint_as_float(u & 0xffff0000u);
}

__global__ __launch_bounds__(64) void ga_wave(
    const float* __restrict__ x,            // (B, L, 4)
    const float* __restrict__ sbp, const float* __restrict__ vsp,
    const float* __restrict__ vbp, const float* __restrict__ bwp,
    const float* __restrict__ WQ,  const float* __restrict__ WK,
    const float* __restrict__ WV,  const float* __restrict__ wh,
    const float* __restrict__ bhp,
    float* __restrict__ out,                // pred (B*T) then weights (B*T*8)
    int B, int L)
{
    const int T  = L - LOOKBACK;
    const int bb = blockIdx.y;
    const int t0 = blockIdx.x * TPW;
    const int j  = threadIdx.x;             // lane 0..63

    __shared__ float    sP[WS_N];
    __shared__ unsigned sK[64 * RST];       // bf16-packed K rows for this wave
    __shared__ float    sVW[64];

    const float* xb = x + (size_t)bb * L * 4;

    // ---- Phase 0: per-wave parameter collapse ----
    const int ch = j & 31;
    {
        const float* W = (j < 32) ? WK : WQ;
        float w[11];
#pragma unroll
        for (int i = 0; i < 11; ++i) w[i] = W[i * HID + ch];

        const float b0 = bwp[0], b1 = bwp[1], b2 = bwp[2];
        const float b3 = bwp[3], b4 = bwp[4], b5 = bwp[5];
        const float v0 = vsp[0], v1 = vsp[1], v2 = vsp[2], v3 = vsp[3];
        const float u0 = vbp[0], u1 = vbp[1], u2 = vbp[2], u3 = vbp[3];
        const float s0 = 1.0f + sbp[0];

        // x_d coefficients. BIV_I=[0,0,0,1,1,2], BIV_J=[1,2,3,2,3,3]
        const float a0 = v0*w[1] + b0*w[5] + b1*w[6] + b2*w[7];
        const float a1 = v1*w[2] - b0*w[5] + b3*w[8] + b4*w[9];
        const float a2 = v2*w[3] - b1*w[6] - b3*w[8] + b5*w[10];
        const float a3 = v3*w[4] - b2*w[7] - b4*w[9] - b5*w[10];
        const float c  = s0*w[0] + u0*w[1] + u1*w[2] + u2*w[3] + u3*w[4];

        const int ab = (j < 32) ? WS_AK : WS_AQ;
        const int cb = (j < 32) ? WS_CK : WS_CQ;
        sP[ab + 0*HID + ch] = a0; sP[ab + 1*HID + ch] = a1;
        sP[ab + 2*HID + ch] = a2; sP[ab + 3*HID + ch] = a3;
        sP[cb + ch] = c;
    }
    if (j < 32) {
        float w[11];
#pragma unroll
        for (int i = 0; i < 11; ++i) w[i] = WV[i * HID + ch];
        const float b0 = bwp[0], b1 = bwp[1], b2 = bwp[2];
        const float b3 = bwp[3], b4 = bwp[4], b5 = bwp[5];
        const float v0 = vsp[0], v1 = vsp[1], v2 = vsp[2], v3 = vsp[3];
        const float u0 = vbp[0], u1 = vbp[1], u2 = vbp[2], u3 = vbp[3];
        const float s0 = 1.0f + sbp[0];

        const float a0 = v0*w[1] + b0*w[5] + b1*w[6] + b2*w[7];
        const float a1 = v1*w[2] - b0*w[5] + b3*w[8] + b4*w[9];
        const float a2 = v2*w[3] - b1*w[6] - b3*w[8] + b5*w[10];
        const float a3 = v3*w[4] - b2*w[7] - b4*w[9] - b5*w[10];
        const float c  = s0*w[0] + u0*w[1] + u1*w[2] + u2*w[3] + u3*w[4];

        const float ww = wh[ch];
        float r0 = a0*ww, r1 = a1*ww, r2 = a2*ww, r3 = a3*ww, r4 = c*ww;
#pragma unroll
        for (int off = 16; off > 0; off >>= 1) {      // partners stay in 0..31
            r0 += __shfl_xor(r0, off, 64);
            r1 += __shfl_xor(r1, off, 64);
            r2 += __shfl_xor(r2, off, 64);
            r3 += __shfl_xor(r3, off, 64);
            r4 += __shfl_xor(r4, off, 64);
        }
        if (ch == 0) {
            sP[WS_AVW + 0] = r0; sP[WS_AVW + 1] = r1;
            sP[WS_AVW + 2] = r2; sP[WS_AVW + 3] = r3;
            sP[WS_CVW]     = r4;
        }
    }
    __syncthreads();    // single-wave: nearly free

    // ---- load this lane's K-row x and query x ----
    const int rr = min(t0 + j, L - 1);
    const float4 xv = *reinterpret_cast<const float4*>(xb + (size_t)rr * 4);
    const int rq = min(t0 + j + LOOKBACK, L - 1);
    const float4 xq = *reinterpret_cast<const float4*>(xb + (size_t)rq * 4);

    // ---- vw for this row ----
    sVW[j] = sP[WS_CVW] + xv.x*sP[WS_AVW+0] + xv.y*sP[WS_AVW+1]
           + xv.z*sP[WS_AVW+2] + xv.w*sP[WS_AVW+3];

    // ---- K-row gen (bf16-packed into LDS) ----
    unsigned* dst = &sK[j * RST];
#pragma unroll
    for (int oc = 0; oc < 4; ++oc) {
        const int hb = oc * 8;
        const float4 c0 = *reinterpret_cast<const float4*>(&sP[WS_CK + hb]);
        const float4 c1 = *reinterpret_cast<const float4*>(&sP[WS_CK + hb + 4]);
        const float4 a0l = *reinterpret_cast<const float4*>(&sP[WS_AK + 0*HID + hb]);
        const float4 a0h = *reinterpret_cast<const float4*>(&sP[WS_AK + 0*HID + hb + 4]);
        const float4 a1l = *reinterpret_cast<const float4*>(&sP[WS_AK + 1*HID + hb]);
        const float4 a1h = *reinterpret_cast<const float4*>(&sP[WS_AK + 1*HID + hb + 4]);
        const float4 a2l = *reinterpret_cast<const float4*>(&sP[WS_AK + 2*HID + hb]);
        const float4 a2h = *reinterpret_cast<const float4*>(&sP[WS_AK + 2*HID + hb + 4]);
        const float4 a3l = *reinterpret_cast<const float4*>(&sP[WS_AK + 3*HID + hb]);
        const float4 a3h = *reinterpret_cast<const float4*>(&sP[WS_AK + 3*HID + hb + 4]);

        const float z0 = phi1(c0.x + xv.x*a0l.x + xv.y*a1l.x + xv.z*a2l.x + xv.w*a3l.x);
        const float z1 = phi1(c0.y + xv.x*a0l.y + xv.y*a1l.y + xv.z*a2l.y + xv.w*a3l.y);
        const float z2 = phi1(c0.z + xv.x*a0l.z + xv.y*a1l.z + xv.z*a2l.z + xv.w*a3l.z);
        const float z3 = phi1(c0.w + xv.x*a0l.w + xv.y*a1l.w + xv.z*a2l.w + xv.w*a3l.w);
        const float z4 = phi1(c1.x + xv.x*a0h.x + xv.y*a1h.x + xv.z*a2h.x + xv.w*a3h.x);
        const float z5 = phi1(c1.y + xv.x*a0h.y + xv.y*a1h.y + xv.z*a2h.y + xv.w*a3h.y);
        const float z6 = phi1(c1.z + xv.x*a0h.z + xv.y*a1h.z + xv.z*a2h.z + xv.w*a3h.z);
        const float z7 = phi1(c1.w + xv.x*a0h.w + xv.y*a1h.w + xv.z*a2h.w + xv.w*a3h.w);

        *reinterpret_cast<uint4*>(dst + oc*4) = make_uint4(
            pack_bf16(z0, z1), pack_bf16(z2, z3),
            pack_bf16(z4, z5), pack_bf16(z6, z7));
    }

    // ---- q gen (f32 in registers) ----
    float q[HID];
#pragma unroll
    for (int oc = 0; oc < 4; ++oc) {
        const int hb = oc * 8;
        const float4 c0 = *reinterpret_cast<const float4*>(&sP[WS_CQ + hb]);
        const float4 c1 = *reinterpret_cast<const float4*>(&sP[WS_CQ + hb + 4]);
        const float4 a0l = *reinterpret_cast<const float4*>(&sP[WS_AQ + 0*HID + hb]);
        const float4 a0h = *reinterpret_cast<const float4*>(&sP[WS_AQ + 0*HID + hb + 4]);
        const float4 a1l = *reinterpret_cast<const float4*>(&sP[WS_AQ + 1*HID + hb]);
        const float4 a1h = *reinterpret_cast<const float4*>(&sP[WS_AQ + 1*HID + hb + 4]);
        const float4 a2l = *reinterpret_cast<const float4*>(&sP[WS_AQ + 2*HID + hb]);
        const float4 a2h = *reinterpret_cast<const float4*>(&sP[WS_AQ + 2*HID + hb + 4]);
        const float4 a3l = *reinterpret_cast<const float4*>(&sP[WS_AQ + 3*HID + hb]);
        const float4 a3h = *reinterpret_cast<const float4*>(&sP[WS_AQ + 3*HID + hb + 4]);

        q[hb+0] = phi1(c0.x + xq.x*a0l.x + xq.y*a1l.x + xq.z*a2l.x + xq.w*a3l.x);
        q[hb+1] = phi1(c0.y + xq.x*a0l.y + xq.y*a1l.y + xq.z*a2l.y + xq.w*a3l.y);
        q[hb+2] = phi1(c0.z + xq.x*a0l.z + xq.y*a1l.z + xq.z*a2l.z + xq.w*a3l.z);
        q[hb+3] = phi1(c0.w + xq.x*a0l.w + xq.y*a1l.w + xq.z*a2l.w + xq.w*a3l.w);
        q[hb+4] = phi1(c1.x + xq.x*a0h.x + xq.y*a1h.x + xq.z*a2h.x + xq.w*a3h.x);
        q[hb+5] = phi1(c1.y + xq.x*a0h.y + xq.y*a1h.y + xq.z*a2h.y + xq.w*a3h.y);
        q[hb+6] = phi1(c1.z + xq.x*a0h.z + xq.y*a1h.z + xq.z*a2h.z + xq.w*a3h.z);
        q[hb+7] = phi1(c1.w + xq.x*a0h.w + xq.y*a1h.w + xq.z*a2h.w + xq.w*a3h.w);
    }
    __syncthreads();    // single-wave: nearly free

    // ---- window dots: rows j..j+7 (all within this wave's 64 rows) ----
    float sc[LOOKBACK];
    float ssum = 0.0f, p = 0.0f;
#pragma unroll
    for (int l = 0; l < LOOKBACK; ++l) {
        const int ri = min(j + l, 63);      // lanes >= 56 produce garbage (unused)
        const unsigned* kr = &sK[ri * RST];
        const uint4 w0 = *reinterpret_cast<const uint4*>(kr);
        const uint4 w1 = *reinterpret_cast<const uint4*>(kr + 4);
        const uint4 w2 = *reinterpret_cast<const uint4*>(kr + 8);
        const uint4 w3 = *reinterpret_cast<const uint4*>(kr + 12);
        float s;
        s  = blo(w0.x)*q[0]  + bhi(w0.x)*q[1]  + blo(w0.y)*q[2]  + bhi(w0.y)*q[3];
        s += blo(w0.z)*q[4]  + bhi(w0.z)*q[5]  + blo(w0.w)*q[6]  + bhi(w0.w)*q[7];
        s += blo(w1.x)*q[8]  + bhi(w1.x)*q[9]  + blo(w1.y)*q[10] + bhi(w1.y)*q[11];
        s += blo(w1.z)*q[12] + bhi(w1.z)*q[13] + blo(w1.w)*q[14] + bhi(w1.w)*q[15];
        s += blo(w2.x)*q[16] + bhi(w2.x)*q[17] + blo(w2.y)*q[18] + bhi(w2.y)*q[19];
        s += blo(w2.z)*q[20] + bhi(w2.z)*q[21] + blo(w2.w)*q[22] + bhi(w2.w)*q[23];
        s += blo(w3.x)*q[24] + bhi(w3.x)*q[25] + blo(w3.y)*q[26] + bhi(w3.y)*q[27];
        s += blo(w3.z)*q[28] + bhi(w3.z)*q[29] + blo(w3.w)*q[30] + bhi(w3.w)*q[31];
        sc[l] = s;
        ssum += s;
        p += s * sVW[ri];
    }
    const float inv = 1.0f / (ssum + EPS);

    const int t = t0 + j;
    if (j < TPW && t < T) {
        out[(size_t)bb * T + t] = p * inv + bhp[0];
        float* wout = out + (size_t)B * T + ((size_t)bb * T + t) * LOOKBACK;
        *reinterpret_cast<float4*>(wout) =
            make_float4(sc[0]*inv, sc[1]*inv, sc[2]*inv, sc[3]*inv);
        *reinterpret_cast<float4*>(wout + 4) =
            make_float4(sc[4]*inv, sc[5]*inv, sc[6]*inv, sc[7]*inv);
    }
}

extern "C" void kernel_launch(void* const* d_in, const int* in_sizes, int n_in,
                              void* d_out, int out_size, void* d_ws, size_t ws_size,
                              hipStream_t stream) {
    const float* x  = (const float*)d_in[0];
    const float* sb = (const float*)d_in[1];
    const float* vs = (const float*)d_in[2];
    const float* vb = (const float*)d_in[3];
    const float* bw = (const float*)d_in[4];
    const float* WQ = (const float*)d_in[5];
    const float* WK = (const float*)d_in[6];
    const float* WV = (const float*)d_in[7];
    const float* wh = (const float*)d_in[8];
    const float* bh = (const float*)d_in[9];
    float* out = (float*)d_out;

    // in_sizes[0] = B*L*4 ; out_size = B*(L-LOOKBACK)*(1+LOOKBACK)
    const long long bl = (long long)in_sizes[0] / 4;            // B*L
    const long long bt = (long long)out_size / (1 + LOOKBACK);  // B*(L-8)
    const int B = (int)((bl - bt) / LOOKBACK);
    const int L = (int)(bl / B);
    const int T = L - LOOKBACK;

    dim3 grid((T + TPW - 1) / TPW, B);
    ga_wave<<<grid, 64, 0, stream>>>(x, sb, vs, vb, bw, WQ, WK, WV, wh, bh,
                                     out, B, L);
}

// Round 9
// 12.169 us; speedup vs baseline: 1.3140x; 1.3140x over previous
//
#include <hip/hip_runtime.h>

#define LOOKBACK 8
#define HID 32
#define TB 256
#define NPOS (TB + LOOKBACK)
#define KST 36          // floats; 144B row stride: 16B-aligned, spreads banks
#define EPS 1e-6f

// sP (LDS) float layout
#define WS_AQ  0     // [4][32]  A_Q
#define WS_CQ  128   // [32]     c_Q
#define WS_AK  160   // [4][32]  A_K
#define WS_CK  288   // [32]     c_K
#define WS_AVW 320   // [4]      a_vw
#define WS_CVW 324   // scalar   c_vw
#define WS_N   336

__device__ __forceinline__ float phi1(float z) {
    return (z >= 0.0f ? z : 0.01f * z) + 1.0f;
}

__global__ __launch_bounds__(TB) void ga_fused(
    const float* __restrict__ x,            // (B, L, 4)
    const float* __restrict__ sbp,          // (1,)
    const float* __restrict__ vsp,          // (4,)
    const float* __restrict__ vbp,          // (4,)
    const float* __restrict__ bwp,          // (6,)
    const float* __restrict__ WQ,           // (11, 32)
    const float* __restrict__ WK,
    const float* __restrict__ WV,
    const float* __restrict__ wh,           // (32,)
    const float* __restrict__ bhp,          // scalar
    float* __restrict__ out,                // pred (B*T) then weights (B*T*8)
    int B, int L)
{
    const int T   = L - LOOKBACK;
    const int bb  = blockIdx.y;
    const int t0  = blockIdx.x * TB;
    const int tid = threadIdx.x;

    __shared__ float sP[WS_N];
    __shared__ float sK[NPOS * KST];
    __shared__ float sVW[NPOS];

    // ---- prefetch this thread's query x (hides under collapse + phase A) ----
    const int t = t0 + tid;
    const bool valid = (t < T);
    const float4 xq = *reinterpret_cast<const float4*>(
        x + ((size_t)bb * L + (valid ? t + LOOKBACK : 0)) * 4);

    // ---- Phase 0: in-block parameter collapse (threads 0..95) ----
    if (tid < 96) {
        const int h   = tid & 31;
        const int mat = tid >> 5;            // 0=Q, 1=K, 2=V
        const float* W = (mat == 0) ? WQ : (mat == 1) ? WK : WV;
        float w[11];
#pragma unroll
        for (int j = 0; j < 11; ++j) w[j] = W[j * HID + h];

        const float b0 = bwp[0], b1 = bwp[1], b2 = bwp[2];
        const float b3 = bwp[3], b4 = bwp[4], b5 = bwp[5];
        const float v0 = vsp[0], v1 = vsp[1], v2 = vsp[2], v3 = vsp[3];
        const float u0 = vbp[0], u1 = vbp[1], u2 = vbp[2], u3 = vbp[3];
        const float s0 = 1.0f + sbp[0];

        // x_d coefficients. BIV_I=[0,0,0,1,1,2], BIV_J=[1,2,3,2,3,3]
        const float a0 = v0*w[1] + b0*w[5] + b1*w[6] + b2*w[7];
        const float a1 = v1*w[2] - b0*w[5] + b3*w[8] + b4*w[9];
        const float a2 = v2*w[3] - b1*w[6] - b3*w[8] + b5*w[10];
        const float a3 = v3*w[4] - b2*w[7] - b4*w[9] - b5*w[10];
        const float c  = s0*w[0] + u0*w[1] + u1*w[2] + u2*w[3] + u3*w[4];

        if (mat == 0) {
            sP[WS_AQ + 0*HID + h] = a0; sP[WS_AQ + 1*HID + h] = a1;
            sP[WS_AQ + 2*HID + h] = a2; sP[WS_AQ + 3*HID + h] = a3;
            sP[WS_CQ + h] = c;
        } else if (mat == 1) {
            sP[WS_AK + 0*HID + h] = a0; sP[WS_AK + 1*HID + h] = a1;
            sP[WS_AK + 2*HID + h] = a2; sP[WS_AK + 3*HID + h] = a3;
            sP[WS_CK + h] = c;
        } else {
            // a_vw[d] = sum_h a_d[h] * wh[h];  c_vw = sum_h c[h] * wh[h]
            const float ww = wh[h];
            float r[5] = { a0*ww, a1*ww, a2*ww, a3*ww, c*ww };
#pragma unroll
            for (int off = 16; off > 0; off >>= 1) {
#pragma unroll
                for (int i = 0; i < 5; ++i) r[i] += __shfl_down(r[i], off, 32);
            }
            if (h == 0) {
                sP[WS_AVW + 0] = r[0]; sP[WS_AVW + 1] = r[1];
                sP[WS_AVW + 2] = r[2]; sP[WS_AVW + 3] = r[3];
                sP[WS_CVW]     = r[4];
            }
        }
    }
    __syncthreads();

    // ---- Phase A: K rows (phi) + V.w_head for positions [t0, t0+npos) ----
    const float avw0 = sP[WS_AVW + 0], avw1 = sP[WS_AVW + 1];
    const float avw2 = sP[WS_AVW + 2], avw3 = sP[WS_AVW + 3];
    const float cvw  = sP[WS_CVW];

    const int npos = min(NPOS, L - t0);
    for (int pos = tid; pos < npos; pos += TB) {
        const float4 xv = *reinterpret_cast<const float4*>(
            x + ((size_t)bb * L + (t0 + pos)) * 4);

        sVW[pos] = cvw + xv.x*avw0 + xv.y*avw1 + xv.z*avw2 + xv.w*avw3;

#pragma unroll
        for (int g = 0; g < 8; ++g) {
            float4 a = *reinterpret_cast<const float4*>(&sP[WS_CK + g*4]);
#pragma unroll
            for (int d = 0; d < 4; ++d) {
                const float xd = (d == 0) ? xv.x : (d == 1) ? xv.y
                               : (d == 2) ? xv.z : xv.w;
                const float4 ad = *reinterpret_cast<const float4*>(
                    &sP[WS_AK + d*HID + g*4]);
                a.x += xd*ad.x; a.y += xd*ad.y; a.z += xd*ad.z; a.w += xd*ad.w;
            }
            a.x = phi1(a.x); a.y = phi1(a.y); a.z = phi1(a.z); a.w = phi1(a.w);
            *reinterpret_cast<float4*>(&sK[pos * KST + g * 4]) = a;
        }
    }
    __syncthreads();

    // ---- Phase B: per-thread q, 8 window dots, outputs ----
    if (!valid) return;

    float q[HID];
#pragma unroll
    for (int g = 0; g < 8; ++g) {
        float4 z = *reinterpret_cast<const float4*>(&sP[WS_CQ + g*4]);
#pragma unroll
        for (int d = 0; d < 4; ++d) {
            const float xd = (d == 0) ? xq.x : (d == 1) ? xq.y
                           : (d == 2) ? xq.z : xq.w;
            const float4 ad = *reinterpret_cast<const float4*>(
                &sP[WS_AQ + d*HID + g*4]);
            z.x += xd*ad.x; z.y += xd*ad.y; z.z += xd*ad.z; z.w += xd*ad.w;
        }
        q[g*4+0] = phi1(z.x); q[g*4+1] = phi1(z.y);
        q[g*4+2] = phi1(z.z); q[g*4+3] = phi1(z.w);
    }

    float sc[LOOKBACK];
#pragma unroll
    for (int l = 0; l < LOOKBACK; ++l) sc[l] = 0.0f;

#pragma unroll
    for (int g = 0; g < 8; ++g) {
        const float qx = q[g*4+0], qy = q[g*4+1], qz = q[g*4+2], qw = q[g*4+3];
#pragma unroll
        for (int l = 0; l < LOOKBACK; ++l) {
            const float4 kg = *reinterpret_cast<const float4*>(
                &sK[(tid + l) * KST + g * 4]);
            sc[l] += qx*kg.x + qy*kg.y + qz*kg.z + qw*kg.w;
        }
    }

    float ssum = 0.0f, p = 0.0f;
#pragma unroll
    for (int l = 0; l < LOOKBACK; ++l) {
        ssum += sc[l];
        p    += sc[l] * sVW[tid + l];
    }
    const float inv = 1.0f / (ssum + EPS);

    out[(size_t)bb * T + t] = p * inv + bhp[0];

    float* wout = out + (size_t)B * T + ((size_t)bb * T + t) * LOOKBACK;
    *reinterpret_cast<float4*>(wout) =
        make_float4(sc[0]*inv, sc[1]*inv, sc[2]*inv, sc[3]*inv);
    *reinterpret_cast<float4*>(wout + 4) =
        make_float4(sc[4]*inv, sc[5]*inv, sc[6]*inv, sc[7]*inv);
}

extern "C" void kernel_launch(void* const* d_in, const int* in_sizes, int n_in,
                              void* d_out, int out_size, void* d_ws, size_t ws_size,
                              hipStream_t stream) {
    const float* x  = (const float*)d_in[0];
    const float* sb = (const float*)d_in[1];
    const float* vs = (const float*)d_in[2];
    const float* vb = (const float*)d_in[3];
    const float* bw = (const float*)d_in[4];
    const float* WQ = (const float*)d_in[5];
    const float* WK = (const float*)d_in[6];
    const float* WV = (const float*)d_in[7];
    const float* wh = (const float*)d_in[8];
    const float* bh = (const float*)d_in[9];
    float* out = (float*)d_out;

    // in_sizes[0] = B*L*4 ; out_size = B*(L-LOOKBACK)*(1+LOOKBACK)
    const long long bl = (long long)in_sizes[0] / 4;            // B*L
    const long long bt = (long long)out_size / (1 + LOOKBACK);  // B*(L-8)
    const int B = (int)((bl - bt) / LOOKBACK);
    const int L = (int)(bl / B);
    const int T = L - LOOKBACK;

    dim3 grid((T + TB - 1) / TB, B);
    ga_fused<<<grid, TB, 0, stream>>>(x, sb, vs, vb, bw, WQ, WK, WV, wh, bh,
                                      out, B, L);
}